// Round 5
// baseline (392.618 us; speedup 1.0000x reference)
//
#include <hip/hip_runtime.h>
#include <cstdint>
#include <cstddef>

// C[4096,4096] = sum_r input[r] @ weight[r]^T  == GEMM M=N=4096, K=8192, fp32 out.
// Phase 1: fp32 -> bf16 linear cast (unchanged — at BW roofline).
// Phase 2: 256x256-tile bf16 MFMA GEMM, DS-balanced read-ahead pipeline (R5):
//   R4 post-mortem: MfmaUtil 57% with per-phase DS read work 768/384/0/1152 cyc
//   vs 620-cyc MFMA windows -> P4's DS burst is exposed. R5 balances DS to
//   8/4/8/4 reads + one 2-load stage per phase:
//     P1: read aHi(t)      | stage A0(t+2)->p | Q1(aLo,bLo)  | bar
//     P2: read bHi(t)      | stage B0(t+2)->p | Q2(aHi,bLo)  | vmcnt(4) | bar
//     P3: read aLo'(t+1)   | stage A1(t+2)->p | Q3(aLo,bHi)  | bar
//     P4: read bLo'(t+1)   | stage B1(t+2)->p | Q4(aHi,bHi)  | bar
//   vmcnt(4) at end-P2 (entering P1: 8 outstanding = t+1's halves; +4 staged
//   P1/P2) drains tile t+1 exactly -> its reads in P3/P4 are safe.
//   Register double-buffer aLo/bLo (new tile's frags land in the alternate set
//   while Q3/Q4 consume the current set) — KTILE alternates sets per call.
//   Hazard ledger: every LDS region has uniform 2-barrier separation between
//   last read and next stage (A-lo: rd P3(t-1)/st P1(t); A-hi: P1/P3;
//   B-lo: P4(t-1)/P2; B-hi: P2/P4). Same-phase read+stage are disjoint regions.

#define M_DIM 4096
#define N_DIM 4096
#define K_DIM 8192
#define K_LOCAL 1024
#define RANKS 8

typedef __bf16 bf16x8 __attribute__((ext_vector_type(8)));
typedef float f32x4 __attribute__((ext_vector_type(4)));

__device__ __forceinline__ unsigned short f2bf(float f) {
    unsigned int u = __float_as_uint(f);
    unsigned int r = (u + 0x7fffu + ((u >> 16) & 1u)) >> 16;
    return (unsigned short)r;
}

// ---------- Phase 1: linear fp32 -> bf16 cast ----------
__global__ __launch_bounds__(256) void convert_cast(
    const float* __restrict__ srcA, unsigned short* __restrict__ dstA,
    const float* __restrict__ srcB, unsigned short* __restrict__ dstB,
    int blocks_per_tensor) {
    const float* src = srcA;
    unsigned short* dst = dstA;
    int b = blockIdx.x;
    if (b >= blocks_per_tensor) { b -= blocks_per_tensor; src = srcB; dst = dstB; }
    size_t base = (size_t)b * 4096 + threadIdx.x * 4;
#pragma unroll
    for (int i = 0; i < 4; ++i) {
        size_t e = base + i * 1024;
        f32x4 v = __builtin_nontemporal_load((const f32x4*)(src + e));
        ushort4 o;
        o.x = f2bf(v.x); o.y = f2bf(v.y); o.z = f2bf(v.z); o.w = f2bf(v.w);
        *(ushort4*)(dst + e) = o;
    }
}

// ---------- shared helpers ----------
__device__ __forceinline__ void gll16(const unsigned short* g, unsigned short* l) {
    __builtin_amdgcn_global_load_lds(
        (const __attribute__((address_space(1))) void*)g,
        (__attribute__((address_space(3))) void*)l,
        16, 0, 0);
}

__device__ __forceinline__ int k_off(int t) {
    // element offset of K-tile t in [R][4096][K_LOCAL]: r = t>>4, kl = (t&15)*64
    return ((t >> 4) << 22) | ((t & 15) << 6);
}

// ---------- Phase 2 macros ----------
// LDS (ushorts): A[buf][half] at (buf*2+half)*8192, B at 32768 + same. 128 KiB.
#define VM8 asm volatile("s_waitcnt vmcnt(8)" ::: "memory")
#define VM4 asm volatile("s_waitcnt vmcnt(4)" ::: "memory")
#define VM0 asm volatile("s_waitcnt vmcnt(0)" ::: "memory")
#define VMNONE ((void)0)
#define BAR __builtin_amdgcn_s_barrier();

#define STAGE_A(TOFF, HALF, PBUF) { \
    _Pragma("unroll") for (int j_ = 0; j_ < 2; ++j_) \
        gll16(A + (size_t)((TOFF) + (HALF) * 131072 + thrA[j_]), \
              smem + (PBUF) * 16384 + (HALF) * 8192 + ldsOff[j_]); }

#define STAGE_B(TOFF, HALF, PBUF) { \
    _Pragma("unroll") for (int j_ = 0; j_ < 2; ++j_) \
        gll16(B + (size_t)((TOFF) + (HALF) * 131072 + thrB[j_]), \
              smem + 32768 + (PBUF) * 16384 + (HALF) * 8192 + ldsOff[j_]); }

#define READ_A(DST, BASE, MOFF) { \
    _Pragma("unroll") for (int ks_ = 0; ks_ < 2; ++ks_) \
        _Pragma("unroll") for (int mm_ = 0; mm_ < 4; ++mm_) \
            DST[ks_][mm_] = *(const bf16x8*)&(BASE)[(((MOFF) + mm_) * 16 + l15) * 64 + (ks_ ? swz1 : swz0)]; }

#define READ_B(DST, BASE, NJ0) { \
    _Pragma("unroll") for (int ks_ = 0; ks_ < 2; ++ks_) \
        _Pragma("unroll") for (int nn_ = 0; nn_ < 2; ++nn_) \
            DST[ks_][nn_] = *(const bf16x8*)&(BASE)[(bRowBase + ((NJ0) + nn_) * 16 + l15) * 64 + (ks_ ? swz1 : swz0)]; }

#define QUAD(AF, BF, MI0, NJ0) { \
    __builtin_amdgcn_s_setprio(1); \
    _Pragma("unroll") for (int ks_ = 0; ks_ < 2; ++ks_) \
        _Pragma("unroll") for (int mm_ = 0; mm_ < 4; ++mm_) \
            _Pragma("unroll") for (int nn_ = 0; nn_ < 2; ++nn_) \
                acc[(MI0) + mm_][(NJ0) + nn_] = __builtin_amdgcn_mfma_f32_16x16x32_bf16( \
                    AF[ks_][mm_], BF[ks_][nn_], acc[(MI0) + mm_][(NJ0) + nn_], 0, 0, 0); \
    __builtin_amdgcn_s_setprio(0); }

// One K-tile = 4 balanced phases, ONE barrier each. ALO_C/BLO_C = current
// tile's low frags; ALO_N/BLO_N = register set receiving tile t+1's low frags.
#define KTILE(PBUF, KT, S, SR, VMOP, ALO_C, BLO_C, ALO_N, BLO_N) { \
    const int t2off_ = k_off((KT) + 2); \
    unsigned short* aC_ = smem + (PBUF) * 16384 + wmIdx * 8192; \
    unsigned short* bC_ = smem + 32768 + (PBUF) * 16384 + bHalfSel * 8192; \
    unsigned short* aN_ = smem + ((PBUF) ^ 1) * 16384 + wmIdx * 8192; \
    unsigned short* bN_ = smem + 32768 + ((PBUF) ^ 1) * 16384 + bHalfSel * 8192; \
    /* P1 */ \
    READ_A(aHi, aC_, 4) \
    if (S) { STAGE_A(t2off_, 0, (PBUF)) } \
    QUAD(ALO_C, BLO_C, 0, 0) \
    BAR \
    /* P2 */ \
    READ_B(bHi, bC_, 2) \
    if (S) { STAGE_B(t2off_, 0, (PBUF)) } \
    QUAD(aHi, BLO_C, 4, 0) \
    VMOP; \
    BAR \
    /* P3 */ \
    if (SR) { READ_A(ALO_N, aN_, 0) } \
    if (S) { STAGE_A(t2off_, 1, (PBUF)) } \
    QUAD(ALO_C, bHi, 0, 2) \
    BAR \
    /* P4 */ \
    if (SR) { READ_B(BLO_N, bN_, 0) } \
    if (S) { STAGE_B(t2off_, 1, (PBUF)) } \
    QUAD(aHi, bHi, 4, 2) \
    BAR \
}

__global__ __launch_bounds__(512, 2) void gemm_bf16_8ph(
    const unsigned short* __restrict__ A,  // [R, M, K_LOCAL] bf16
    const unsigned short* __restrict__ B,  // [R, N, K_LOCAL] bf16
    float* __restrict__ C) {               // [M, N] fp32
    extern __shared__ unsigned short smem[];  // 131072 B

    const int tid = threadIdx.x;
    const int lane = tid & 63;
    const int wave = tid >> 6;        // 0..7
    const int wmIdx = wave >> 2;      // 0..1  (128-row M half)
    const int wn = wave & 3;          // 0..3  (64-col N slice)
    const int l15 = lane & 15;
    const int l4 = lane >> 4;
    const int bHalfSel = wn >> 1;
    const int bRowBase = (wn & 1) * 64;

    // XCD-aware mapping: 16x16 tile grid; XCD x owns an 8x4 region.
    const int bid = blockIdx.x;       // 0..255
    const int xcd = bid & 7;
    const int idx = bid >> 3;         // 0..31
    const int tm = (xcd >> 2) * 8 + (idx >> 2);
    const int tn = (xcd & 3) * 4 + (idx & 3);
    const int bm0 = tm * 256;
    const int bn0 = tn * 256;

    // Staging offsets: half-tile = 128 rows x 64 cols; chunk cc = j*512 + tid
    // -> (row = cc>>3, pos = cc&7), XOR swizzle applied on the global source.
    int thrA[2], thrB[2], ldsOff[2];
#pragma unroll
    for (int j = 0; j < 2; ++j) {
        int cc = j * 512 + tid;
        int row = cc >> 3;
        int col = ((cc & 7) ^ (row & 7)) * 8;
        thrA[j] = (bm0 + row) * K_LOCAL + col;
        thrB[j] = (bn0 + row) * K_LOCAL + col;
        ldsOff[j] = cc * 8;
    }

    const int swz0 = ((0 + l4) ^ (l15 & 7)) * 8;  // ks = 0
    const int swz1 = ((4 + l4) ^ (l15 & 7)) * 8;  // ks = 1

    bf16x8 aLo[2][4], aLo2[2][4], aHi[2][4], bLo[2][2], bLo2[2][2], bHi[2][2];
    f32x4 acc[8][4] = {};

    // Prologue: stage tile0 (buf0) + tile1 (buf1) fully (16 loads);
    // vmcnt(8) drains tile0, keeps tile1's 8 in flight (= steady-state entry);
    // preload aLo/bLo(0); extra barrier so P1(0)'s stage into buf0-A-lo is
    // >=1 barrier after the preload reads.
    STAGE_A(0, 0, 0)
    STAGE_A(0, 1, 0)
    STAGE_B(0, 0, 0)
    STAGE_B(0, 1, 0)
    STAGE_A(64, 0, 1)
    STAGE_A(64, 1, 1)
    STAGE_B(64, 0, 1)
    STAGE_B(64, 1, 1)
    VM8;
    BAR
    {
        unsigned short* a0_ = smem + wmIdx * 8192;
        unsigned short* b0_ = smem + 32768 + bHalfSel * 8192;
        READ_A(aLo, a0_, 0)
        READ_B(bLo, b0_, 0)
    }
    BAR

#pragma unroll 1
    for (int kt = 0; kt < 126; kt += 2) {
        KTILE(0, kt, 1, 1, VM4, aLo, bLo, aLo2, bLo2)
        KTILE(1, kt + 1, 1, 1, VM4, aLo2, bLo2, aLo, bLo)
    }
    KTILE(0, 126, 0, 1, VM0, aLo, bLo, aLo2, bLo2)      // no stages; drain t127
    KTILE(1, 127, 0, 0, VMNONE, aLo2, bLo2, aLo, bLo)   // pure compute

    // epilogue: C/D layout col = lane&15, row = (lane>>4)*4 + reg
#pragma unroll
    for (int mi = 0; mi < 8; ++mi) {
        int row0 = bm0 + wmIdx * 128 + mi * 16 + l4 * 4;
#pragma unroll
        for (int nj = 0; nj < 4; ++nj) {
            int col = bn0 + wn * 64 + nj * 16 + l15;
#pragma unroll
            for (int r = 0; r < 4; ++r)
                C[(size_t)(row0 + r) * N_DIM + col] = acc[mi][nj][r];
        }
    }
}

// ---------- Fallback A: 128x128 m97-structure kernel ----------
__global__ __launch_bounds__(256) void gemm_bf16_128(
    const unsigned short* __restrict__ A,
    const unsigned short* __restrict__ B,
    float* __restrict__ C) {
    __shared__ __align__(16) unsigned short As[128 * 64];
    __shared__ __align__(16) unsigned short Bs[128 * 64];

    const int tid = threadIdx.x;
    const int lane = tid & 63;
    const int wave = tid >> 6;
    const int wm = (wave >> 1) * 64;
    const int wnn = (wave & 1) * 64;
    const int l15 = lane & 15;
    const int l4 = lane >> 4;

    const int bid = blockIdx.x;
    const int xcd = bid & 7;
    const int q = bid >> 3;
    const int st = (q >> 2) * 8 + xcd;
    const int pos = q & 3;
    const int bm0 = ((st >> 4) * 2 + (pos >> 1)) * 128;
    const int bn0 = ((st & 15) * 2 + (pos & 1)) * 128;

    const unsigned short* ga[4];
    const unsigned short* gb[4];
    int lo[4];
#pragma unroll
    for (int p = 0; p < 4; ++p) {
        int cc = p * 256 + tid;
        int row = cc >> 3;
        int cpos = cc & 7;
        int col = (cpos ^ (row & 7)) * 8;
        ga[p] = A + (size_t)(bm0 + row) * K_LOCAL + col;
        gb[p] = B + (size_t)(bn0 + row) * K_LOCAL + col;
        lo[p] = cc * 8;
    }

    const int swz0 = ((l4 + 0) ^ (l15 & 7)) * 8;
    const int swz1 = ((l4 + 4) ^ (l15 & 7)) * 8;
    const int a_row = (wm + l15) * 64;
    const int b_row = (wnn + l15) * 64;

    f32x4 acc[4][4] = {};

    for (int r = 0; r < RANKS; ++r) {
        const size_t roff = (size_t)r * (M_DIM * (size_t)K_LOCAL);
        for (int kl = 0; kl < K_LOCAL; kl += 64) {
#pragma unroll
            for (int p = 0; p < 4; ++p) {
                gll16(ga[p] + roff + kl, &As[lo[p]]);
                gll16(gb[p] + roff + kl, &Bs[lo[p]]);
            }
            __syncthreads();
#pragma unroll
            for (int ks = 0; ks < 2; ++ks) {
                const int swz = ks ? swz1 : swz0;
                bf16x8 af[4], bfr[4];
#pragma unroll
                for (int i = 0; i < 4; ++i)
                    af[i] = *(const bf16x8*)&As[a_row + i * 16 * 64 + swz];
#pragma unroll
                for (int j = 0; j < 4; ++j)
                    bfr[j] = *(const bf16x8*)&Bs[b_row + j * 16 * 64 + swz];
#pragma unroll
                for (int i = 0; i < 4; ++i)
#pragma unroll
                    for (int j = 0; j < 4; ++j)
                        acc[i][j] = __builtin_amdgcn_mfma_f32_16x16x32_bf16(
                            af[i], bfr[j], acc[i][j], 0, 0, 0);
            }
            __syncthreads();
        }
    }

#pragma unroll
    for (int i = 0; i < 4; ++i) {
        int row0 = bm0 + wm + i * 16 + l4 * 4;
#pragma unroll
        for (int j = 0; j < 4; ++j) {
            int col = bn0 + wnn + j * 16 + l15;
#pragma unroll
            for (int r = 0; r < 4; ++r)
                C[(size_t)(row0 + r) * N_DIM + col] = acc[i][j][r];
        }
    }
}

// ---------- Fallback B (ws too small): naive fp32 tiled GEMM ----------
__global__ void gemm_naive(const float* __restrict__ A, const float* __restrict__ B,
                           float* __restrict__ C) {
    __shared__ float As[16][17];
    __shared__ float Bs[16][17];
    int tx = threadIdx.x, ty = threadIdx.y;
    int m = blockIdx.y * 16 + ty;
    int n0 = blockIdx.x * 16;
    float accv = 0.f;
    for (int kt = 0; kt < K_DIM; kt += 16) {
        int r = kt >> 10;
        int k = (kt & 1023) + tx;
        As[ty][tx] = A[((size_t)r * M_DIM + m) * K_LOCAL + k];
        Bs[ty][tx] = B[((size_t)r * N_DIM + (n0 + ty)) * K_LOCAL + k];
        __syncthreads();
#pragma unroll
        for (int kk = 0; kk < 16; ++kk) accv += As[ty][kk] * Bs[tx][kk];
        __syncthreads();
    }
    C[(size_t)m * N_DIM + n0 + tx] = accv;
}

extern "C" void kernel_launch(void* const* d_in, const int* in_sizes, int n_in,
                              void* d_out, int out_size, void* d_ws, size_t ws_size,
                              hipStream_t stream) {
    const float* inp = (const float*)d_in[0];
    const float* wgt = (const float*)d_in[1];
    float* out = (float*)d_out;

    const size_t elems = (size_t)M_DIM * K_DIM;              // 33,554,432 per tensor
    const size_t need = 2 * elems * sizeof(unsigned short);  // 128 MiB

    if (ws_size >= need) {
        unsigned short* Abf = (unsigned short*)d_ws;
        unsigned short* Bbf = Abf + elems;
        const int bpt = (int)(elems / 4096);  // 8192 blocks per tensor
        convert_cast<<<bpt * 2, 256, 0, stream>>>(inp, Abf, wgt, Bbf, bpt);

        static int dynOK = -1;
        if (dynOK < 0) {
            dynOK = (hipFuncSetAttribute((const void*)gemm_bf16_8ph,
                                         hipFuncAttributeMaxDynamicSharedMemorySize,
                                         131072) == hipSuccess)
                        ? 1
                        : 0;
        }
        if (dynOK) {
            gemm_bf16_8ph<<<256, 512, 131072, stream>>>(Abf, Bbf, out);
        } else {
            gemm_bf16_128<<<1024, 256, 0, stream>>>(Abf, Bbf, out);
        }
    } else {
        dim3 grid(N_DIM / 16, M_DIM / 16);
        dim3 block(16, 16);
        gemm_naive<<<grid, block, 0, stream>>>(inp, wgt, out);
    }
}

// Round 6
// 266.095 us; speedup vs baseline: 1.4755x; 1.4755x over previous
//
#include <hip/hip_runtime.h>
#include <cstdint>
#include <cstddef>

// C[4096,4096] = sum_r input[r] @ weight[r]^T  == GEMM M=N=4096, K=8192, fp32 out.
// Phase 1: fp32 -> bf16 linear cast (unchanged — at BW roofline).
// Phase 2: 256x256-tile bf16 MFMA GEMM, DS-balanced read-ahead pipeline (R6):
//   R4 (222us, 57.6% MfmaUtil): reads one phase ahead, but per-phase DS load
//   was 8/4/2/18 (b128-equiv/wave) -> P4 burst exposed past its MFMA window.
//   R5 (360us): balanced via register double-buffer -> +48 VGPR blew the
//   256/wave cap (128 AGPR acc + 128 VGPR) -> scratch spill (WRITE_SIZE +16MB).
//   R6 = R4 + balance with ZERO extra registers:
//     - vmcnt drain moved end-P3 -> end-P2 as vmcnt(0) (at that point the only
//       outstanding loads are tile t+1's 8, issued >=4 phases earlier).
//     - next-tile aLo reads moved P4 -> P3, placed AFTER Q3 (last consumer) so
//       the same registers are reused WAR-safely in program order.
//   Per K-tile t (buffer p = t&1), quads Q1=aLo*bLo Q2=aHi*bLo Q3=aLo*bHi
//   Q4=aHi*bHi; reads for Qj issued one phase before use:
//     P1: read aHi(t)[8]                      | Q1 | bar
//     P2: read bHi(t)[4]                      | Q2 | vmcnt(0) | bar
//     P3: stage A0(t+2)->p | Q3 | read aLo(t+1)[8 from p^1]  | bar
//     P4: read bLo(t+1)[4] | stage A1,B0,B1(t+2)->p | Q4     | bar
//   DS/phase: 8 / 4 / 10 / 10 (incl. stage writes) vs 620-cyc MFMA windows.
//   Hazards: every LDS region staged >=2 phases after its last ds_read issue
//   (A-lo rd P3 / st P3(+4); A-hi rd P1 / st P4(+3); B-lo rd P4 / st P4(+4);
//   B-hi rd P2 / st P4(+2)); register WARs resolved by program order.

#define M_DIM 4096
#define N_DIM 4096
#define K_DIM 8192
#define K_LOCAL 1024
#define RANKS 8

typedef __bf16 bf16x8 __attribute__((ext_vector_type(8)));
typedef float f32x4 __attribute__((ext_vector_type(4)));

__device__ __forceinline__ unsigned short f2bf(float f) {
    unsigned int u = __float_as_uint(f);
    unsigned int r = (u + 0x7fffu + ((u >> 16) & 1u)) >> 16;
    return (unsigned short)r;
}

// ---------- Phase 1: linear fp32 -> bf16 cast ----------
__global__ __launch_bounds__(256) void convert_cast(
    const float* __restrict__ srcA, unsigned short* __restrict__ dstA,
    const float* __restrict__ srcB, unsigned short* __restrict__ dstB,
    int blocks_per_tensor) {
    const float* src = srcA;
    unsigned short* dst = dstA;
    int b = blockIdx.x;
    if (b >= blocks_per_tensor) { b -= blocks_per_tensor; src = srcB; dst = dstB; }
    size_t base = (size_t)b * 4096 + threadIdx.x * 4;
#pragma unroll
    for (int i = 0; i < 4; ++i) {
        size_t e = base + i * 1024;
        f32x4 v = __builtin_nontemporal_load((const f32x4*)(src + e));
        ushort4 o;
        o.x = f2bf(v.x); o.y = f2bf(v.y); o.z = f2bf(v.z); o.w = f2bf(v.w);
        *(ushort4*)(dst + e) = o;
    }
}

// ---------- shared helpers ----------
__device__ __forceinline__ void gll16(const unsigned short* g, unsigned short* l) {
    __builtin_amdgcn_global_load_lds(
        (const __attribute__((address_space(1))) void*)g,
        (__attribute__((address_space(3))) void*)l,
        16, 0, 0);
}

__device__ __forceinline__ int k_off(int t) {
    // element offset of K-tile t in [R][4096][K_LOCAL]: r = t>>4, kl = (t&15)*64
    return ((t >> 4) << 22) | ((t & 15) << 6);
}

// ---------- Phase 2 macros ----------
// LDS (ushorts): A[buf][half] at (buf*2+half)*8192, B at 32768 + same. 128 KiB.
#define VM8 asm volatile("s_waitcnt vmcnt(8)" ::: "memory")
#define VM0 asm volatile("s_waitcnt vmcnt(0)" ::: "memory")
#define VMNONE ((void)0)
#define BAR __builtin_amdgcn_s_barrier();

#define STAGE_A(TOFF, HALF, PBUF) { \
    _Pragma("unroll") for (int j_ = 0; j_ < 2; ++j_) \
        gll16(A + (size_t)((TOFF) + (HALF) * 131072 + thrA[j_]), \
              smem + (PBUF) * 16384 + (HALF) * 8192 + ldsOff[j_]); }

#define STAGE_B(TOFF, HALF, PBUF) { \
    _Pragma("unroll") for (int j_ = 0; j_ < 2; ++j_) \
        gll16(B + (size_t)((TOFF) + (HALF) * 131072 + thrB[j_]), \
              smem + 32768 + (PBUF) * 16384 + (HALF) * 8192 + ldsOff[j_]); }

#define READ_A(DST, BASE, MOFF) { \
    _Pragma("unroll") for (int ks_ = 0; ks_ < 2; ++ks_) \
        _Pragma("unroll") for (int mm_ = 0; mm_ < 4; ++mm_) \
            DST[ks_][mm_] = *(const bf16x8*)&(BASE)[(((MOFF) + mm_) * 16 + l15) * 64 + (ks_ ? swz1 : swz0)]; }

#define READ_B(DST, BASE, NJ0) { \
    _Pragma("unroll") for (int ks_ = 0; ks_ < 2; ++ks_) \
        _Pragma("unroll") for (int nn_ = 0; nn_ < 2; ++nn_) \
            DST[ks_][nn_] = *(const bf16x8*)&(BASE)[(bRowBase + ((NJ0) + nn_) * 16 + l15) * 64 + (ks_ ? swz1 : swz0)]; }

#define QUAD(AF, BF, MI0, NJ0) { \
    __builtin_amdgcn_s_setprio(1); \
    _Pragma("unroll") for (int ks_ = 0; ks_ < 2; ++ks_) \
        _Pragma("unroll") for (int mm_ = 0; mm_ < 4; ++mm_) \
            _Pragma("unroll") for (int nn_ = 0; nn_ < 2; ++nn_) \
                acc[(MI0) + mm_][(NJ0) + nn_] = __builtin_amdgcn_mfma_f32_16x16x32_bf16( \
                    AF[ks_][mm_], BF[ks_][nn_], acc[(MI0) + mm_][(NJ0) + nn_], 0, 0, 0); \
    __builtin_amdgcn_s_setprio(0); }

// One K-tile = 4 phases, ONE barrier each. Reads one phase ahead of use;
// same-register next-tile reads placed after their last consumer (WAR by
// program order — no extra register buffers).
#define KTILE(PBUF, KT, S, SR, VMOP) { \
    const int t2off_ = k_off((KT) + 2); \
    unsigned short* aC_ = smem + (PBUF) * 16384 + wmIdx * 8192; \
    unsigned short* bC_ = smem + 32768 + (PBUF) * 16384 + bHalfSel * 8192; \
    unsigned short* aN_ = smem + ((PBUF) ^ 1) * 16384 + wmIdx * 8192; \
    unsigned short* bN_ = smem + 32768 + ((PBUF) ^ 1) * 16384 + bHalfSel * 8192; \
    /* P1 */ \
    READ_A(aHi, aC_, 4) \
    QUAD(aLo, bLo, 0, 0) \
    BAR \
    /* P2 */ \
    READ_B(bHi, bC_, 2) \
    QUAD(aHi, bLo, 4, 0) \
    VMOP; \
    BAR \
    /* P3 */ \
    if (S) { STAGE_A(t2off_, 0, (PBUF)) } \
    QUAD(aLo, bHi, 0, 2) \
    if (SR) { READ_A(aLo, aN_, 0) } \
    BAR \
    /* P4 */ \
    if (SR) { READ_B(bLo, bN_, 0) } \
    if (S) { STAGE_A(t2off_, 1, (PBUF)) STAGE_B(t2off_, 0, (PBUF)) STAGE_B(t2off_, 1, (PBUF)) } \
    QUAD(aHi, bHi, 4, 2) \
    BAR \
}

__global__ __launch_bounds__(512, 2) void gemm_bf16_8ph(
    const unsigned short* __restrict__ A,  // [R, M, K_LOCAL] bf16
    const unsigned short* __restrict__ B,  // [R, N, K_LOCAL] bf16
    float* __restrict__ C) {               // [M, N] fp32
    extern __shared__ unsigned short smem[];  // 131072 B

    const int tid = threadIdx.x;
    const int lane = tid & 63;
    const int wave = tid >> 6;        // 0..7
    const int wmIdx = wave >> 2;      // 0..1  (128-row M half)
    const int wn = wave & 3;          // 0..3  (64-col N slice)
    const int l15 = lane & 15;
    const int l4 = lane >> 4;
    const int bHalfSel = wn >> 1;
    const int bRowBase = (wn & 1) * 64;

    // XCD-aware mapping: 16x16 tile grid; XCD x owns an 8x4 region.
    const int bid = blockIdx.x;       // 0..255
    const int xcd = bid & 7;
    const int idx = bid >> 3;         // 0..31
    const int tm = (xcd >> 2) * 8 + (idx >> 2);
    const int tn = (xcd & 3) * 4 + (idx & 3);
    const int bm0 = tm * 256;
    const int bn0 = tn * 256;

    // Staging offsets: half-tile = 128 rows x 64 cols; chunk cc = j*512 + tid
    // -> (row = cc>>3, pos = cc&7), XOR swizzle applied on the global source.
    int thrA[2], thrB[2], ldsOff[2];
#pragma unroll
    for (int j = 0; j < 2; ++j) {
        int cc = j * 512 + tid;
        int row = cc >> 3;
        int col = ((cc & 7) ^ (row & 7)) * 8;
        thrA[j] = (bm0 + row) * K_LOCAL + col;
        thrB[j] = (bn0 + row) * K_LOCAL + col;
        ldsOff[j] = cc * 8;
    }

    const int swz0 = ((0 + l4) ^ (l15 & 7)) * 8;  // ks = 0
    const int swz1 = ((4 + l4) ^ (l15 & 7)) * 8;  // ks = 1

    bf16x8 aLo[2][4], aHi[2][4], bLo[2][2], bHi[2][2];
    f32x4 acc[8][4] = {};

    // Prologue: stage tile0 (buf0, 8 loads) + tile1 (buf1, 8 loads);
    // vmcnt(8) drains tile0, keeps tile1's 8 in flight (= steady-state entry);
    // then preload aLo/bLo(0) registers.
    STAGE_A(0, 0, 0)
    STAGE_A(0, 1, 0)
    STAGE_B(0, 0, 0)
    STAGE_B(0, 1, 0)
    STAGE_A(64, 0, 1)
    STAGE_A(64, 1, 1)
    STAGE_B(64, 0, 1)
    STAGE_B(64, 1, 1)
    VM8;
    BAR
    {
        unsigned short* a0_ = smem + wmIdx * 8192;
        unsigned short* b0_ = smem + 32768 + bHalfSel * 8192;
        READ_A(aLo, a0_, 0)
        READ_B(bLo, b0_, 0)
    }

#pragma unroll 1
    for (int kt = 0; kt < 126; kt += 2) {
        KTILE(0, kt, 1, 1, VM0)
        KTILE(1, kt + 1, 1, 1, VM0)
    }
    KTILE(0, 126, 0, 1, VM0)     // no stages; drain covers tile 127's 8 loads
    KTILE(1, 127, 0, 0, VMNONE)  // pure compute

    // epilogue: C/D layout col = lane&15, row = (lane>>4)*4 + reg
#pragma unroll
    for (int mi = 0; mi < 8; ++mi) {
        int row0 = bm0 + wmIdx * 128 + mi * 16 + l4 * 4;
#pragma unroll
        for (int nj = 0; nj < 4; ++nj) {
            int col = bn0 + wn * 64 + nj * 16 + l15;
#pragma unroll
            for (int r = 0; r < 4; ++r)
                C[(size_t)(row0 + r) * N_DIM + col] = acc[mi][nj][r];
        }
    }
}

// ---------- Fallback A: 128x128 m97-structure kernel ----------
__global__ __launch_bounds__(256) void gemm_bf16_128(
    const unsigned short* __restrict__ A,
    const unsigned short* __restrict__ B,
    float* __restrict__ C) {
    __shared__ __align__(16) unsigned short As[128 * 64];
    __shared__ __align__(16) unsigned short Bs[128 * 64];

    const int tid = threadIdx.x;
    const int lane = tid & 63;
    const int wave = tid >> 6;
    const int wm = (wave >> 1) * 64;
    const int wnn = (wave & 1) * 64;
    const int l15 = lane & 15;
    const int l4 = lane >> 4;

    const int bid = blockIdx.x;
    const int xcd = bid & 7;
    const int q = bid >> 3;
    const int st = (q >> 2) * 8 + xcd;
    const int pos = q & 3;
    const int bm0 = ((st >> 4) * 2 + (pos >> 1)) * 128;
    const int bn0 = ((st & 15) * 2 + (pos & 1)) * 128;

    const unsigned short* ga[4];
    const unsigned short* gb[4];
    int lo[4];
#pragma unroll
    for (int p = 0; p < 4; ++p) {
        int cc = p * 256 + tid;
        int row = cc >> 3;
        int cpos = cc & 7;
        int col = (cpos ^ (row & 7)) * 8;
        ga[p] = A + (size_t)(bm0 + row) * K_LOCAL + col;
        gb[p] = B + (size_t)(bn0 + row) * K_LOCAL + col;
        lo[p] = cc * 8;
    }

    const int swz0 = ((l4 + 0) ^ (l15 & 7)) * 8;
    const int swz1 = ((l4 + 4) ^ (l15 & 7)) * 8;
    const int a_row = (wm + l15) * 64;
    const int b_row = (wnn + l15) * 64;

    f32x4 acc[4][4] = {};

    for (int r = 0; r < RANKS; ++r) {
        const size_t roff = (size_t)r * (M_DIM * (size_t)K_LOCAL);
        for (int kl = 0; kl < K_LOCAL; kl += 64) {
#pragma unroll
            for (int p = 0; p < 4; ++p) {
                gll16(ga[p] + roff + kl, &As[lo[p]]);
                gll16(gb[p] + roff + kl, &Bs[lo[p]]);
            }
            __syncthreads();
#pragma unroll
            for (int ks = 0; ks < 2; ++ks) {
                const int swz = ks ? swz1 : swz0;
                bf16x8 af[4], bfr[4];
#pragma unroll
                for (int i = 0; i < 4; ++i)
                    af[i] = *(const bf16x8*)&As[a_row + i * 16 * 64 + swz];
#pragma unroll
                for (int j = 0; j < 4; ++j)
                    bfr[j] = *(const bf16x8*)&Bs[b_row + j * 16 * 64 + swz];
#pragma unroll
                for (int i = 0; i < 4; ++i)
#pragma unroll
                    for (int j = 0; j < 4; ++j)
                        acc[i][j] = __builtin_amdgcn_mfma_f32_16x16x32_bf16(
                            af[i], bfr[j], acc[i][j], 0, 0, 0);
            }
            __syncthreads();
        }
    }

#pragma unroll
    for (int i = 0; i < 4; ++i) {
        int row0 = bm0 + wm + i * 16 + l4 * 4;
#pragma unroll
        for (int j = 0; j < 4; ++j) {
            int col = bn0 + wnn + j * 16 + l15;
#pragma unroll
            for (int r = 0; r < 4; ++r)
                C[(size_t)(row0 + r) * N_DIM + col] = acc[i][j][r];
        }
    }
}

// ---------- Fallback B (ws too small): naive fp32 tiled GEMM ----------
__global__ void gemm_naive(const float* __restrict__ A, const float* __restrict__ B,
                           float* __restrict__ C) {
    __shared__ float As[16][17];
    __shared__ float Bs[16][17];
    int tx = threadIdx.x, ty = threadIdx.y;
    int m = blockIdx.y * 16 + ty;
    int n0 = blockIdx.x * 16;
    float accv = 0.f;
    for (int kt = 0; kt < K_DIM; kt += 16) {
        int r = kt >> 10;
        int k = (kt & 1023) + tx;
        As[ty][tx] = A[((size_t)r * M_DIM + m) * K_LOCAL + k];
        Bs[ty][tx] = B[((size_t)r * N_DIM + (n0 + ty)) * K_LOCAL + k];
        __syncthreads();
#pragma unroll
        for (int kk = 0; kk < 16; ++kk) accv += As[ty][kk] * Bs[tx][kk];
        __syncthreads();
    }
    C[(size_t)m * N_DIM + n0 + tx] = accv;
}

extern "C" void kernel_launch(void* const* d_in, const int* in_sizes, int n_in,
                              void* d_out, int out_size, void* d_ws, size_t ws_size,
                              hipStream_t stream) {
    const float* inp = (const float*)d_in[0];
    const float* wgt = (const float*)d_in[1];
    float* out = (float*)d_out;

    const size_t elems = (size_t)M_DIM * K_DIM;              // 33,554,432 per tensor
    const size_t need = 2 * elems * sizeof(unsigned short);  // 128 MiB

    if (ws_size >= need) {
        unsigned short* Abf = (unsigned short*)d_ws;
        unsigned short* Bbf = Abf + elems;
        const int bpt = (int)(elems / 4096);  // 8192 blocks per tensor
        convert_cast<<<bpt * 2, 256, 0, stream>>>(inp, Abf, wgt, Bbf, bpt);

        static int dynOK = -1;
        if (dynOK < 0) {
            dynOK = (hipFuncSetAttribute((const void*)gemm_bf16_8ph,
                                         hipFuncAttributeMaxDynamicSharedMemorySize,
                                         131072) == hipSuccess)
                        ? 1
                        : 0;
        }
        if (dynOK) {
            gemm_bf16_8ph<<<256, 512, 131072, stream>>>(Abf, Bbf, out);
        } else {
            gemm_bf16_128<<<1024, 256, 0, stream>>>(Abf, Bbf, out);
        }
    } else {
        dim3 grid(N_DIM / 16, M_DIM / 16);
        dim3 block(16, 16);
        gemm_naive<<<grid, block, 0, stream>>>(inp, wgt, out);
    }
}